// Round 8
// baseline (225.757 us; speedup 1.0000x reference)
//
#include <hip/hip_runtime.h>

// SSIM-1D fused: depthwise Gaussian convs (K=11, zero-pad 5) + rational epilogue.
// R8: R7's register double-buffer + 4-stream algebra, with the occupancy
// throttle removed. R7 post-mortem: launch_bounds(256,2) + 512 blocks capped
// residency at 2 blocks/CU (occ 20%) -> latency exposed. Now: 2048 blocks
// (8 queued/CU), launch_bounds(256,4) (VGPR cap 128, ~5 blocks/CU resident),
// 8 chunk-iterations per block so workgroup launch rate stops limiting
// residency (R1's 16384 short-lived blocks only reached 42% occupancy).
// A/B ping-pong: next chunk's 12 global_load_dwordx4 issue before current
// chunk's compute (sched_barrier-pinned) -> ~900cy HBM latency hidden.

typedef float f4 __attribute__((ext_vector_type(4)));

constexpr int K = 11;
constexpr int OPT = 8;            // outputs per thread per chunk-iteration
constexpr int BLK = 256;          // threads per block
constexpr int CHUNK = OPT * BLK;  // 2048
constexpr int NB = 2048;          // blocks: 8 per CU queued, ~5 resident

struct Buf { f4 x1[6]; f4 x2[6]; };

__device__ __forceinline__ void issue_loads(
    Buf& b, const float* __restrict__ s1, const float* __restrict__ s2,
    int c, int tid, int total)
{
    const int g = c * CHUNK + tid * OPT - 8;  // aligned window base (mult of 4)
#pragma unroll
    for (int i = 0; i < 6; ++i) {
        int a = g + 4 * i;
        a = a < 0 ? 0 : a;                       // only chunk 0, tid 0 (slabs zeroed)
        a = a > total - 4 ? total - 4 : a;       // only last chunk, tid 255 (zeroed)
        b.x1[i] = *(const f4*)(s1 + a);
        b.x2[i] = *(const f4*)(s2 + a);
    }
}

__device__ __forceinline__ void compute_store(
    const Buf& b, float* __restrict__ out, int c, int tid)
{
    // t[i] <-> row position (c*CHUNK + tid*8) - 8 + i, i = 0..23.
    float t1[24], t2[24];
#pragma unroll
    for (int i = 0; i < 6; ++i) {
        *(f4*)&t1[4 * i] = b.x1[i];
        *(f4*)&t2[4 * i] = b.x2[i];
    }
    // Zero-pad at row edges. Chunk parity == column half (N=4096, CPR=2).
    if (((c & 1) == 0) && tid == 0) {
#pragma unroll
        for (int j = 0; j < 8; ++j) { t1[j] = 0.f; t2[j] = 0.f; }
    }
    if (((c & 1) == 1) && tid == BLK - 1) {
#pragma unroll
        for (int j = 16; j < 24; ++j) { t1[j] = 0.f; t2[j] = 0.f; }
    }

    // Sum/diff squared streams, once per window element (t[m+3] = rel pos -5+m).
    float u[18], v[18];
#pragma unroll
    for (int m = 0; m < 18; ++m) {
        float a = t1[m + 3] + t2[m + 3];
        float d = t1[m + 3] - t2[m + 3];
        u[m] = a * a;                 // (s1+s2)^2
        v[m] = d * d;                 // (s1-s2)^2
    }

    // Gaussian(11, 1.5) normalized (matches numpy float32 to ~1e-7); SGPR consts.
    const float Wt[K] = {0.00102838f, 0.00759876f, 0.03600079f, 0.10936070f,
                         0.21300553f, 0.26601172f, 0.21300553f, 0.10936070f,
                         0.03600079f, 0.00759876f, 0.00102838f};
    const float C1 = 1.0e-4f, C2 = 9.0e-4f;

    float res[OPT];
#pragma unroll
    for (int j = 0; j < OPT; ++j) {
        float mu1 = 0.f, mu2 = 0.f, su = 0.f, sv = 0.f;
#pragma unroll
        for (int k = 0; k < K; ++k) {
            float w = Wt[k];
            mu1 = fmaf(w, t1[j + k + 3], mu1);
            mu2 = fmaf(w, t2[j + k + 3], mu2);
            su  = fmaf(w, u[j + k], su);
            sv  = fmaf(w, v[j + k], sv);
        }
        float mu1q  = mu1 * mu1;          // mu1^2
        float mu2q  = mu2 * mu2;          // mu2^2
        float mup   = mu1 * mu2;          // mu1*mu2
        float ms    = 0.5f  * (su + sv);  // m11 + m22
        float m12   = 0.25f * (su - sv);  // E[s1*s2]
        float s12   = m12 - mup;          // sigma12
        float sden  = ms - mu1q - mu2q + C2;           // sigma1^2+sigma2^2+C2
        float num   = fmaf(2.f, mup, C1) * fmaf(2.f, s12, C2);
        float den   = (mu1q + mu2q + C1) * sden;
        float ssim  = num * __builtin_amdgcn_rcpf(den);  // den >= C1*C2 > 0
        res[j] = 0.5f - 0.5f * ssim;                     // 1 - (ssim+1)/2
    }

    f4* op = (f4*)(out + c * CHUNK + tid * OPT);
    op[0] = *(f4*)&res[0];
    op[1] = *(f4*)&res[4];
}

__global__ __launch_bounds__(BLK, 4) void ssim1d_kernel(
    const float* __restrict__ s1, const float* __restrict__ s2,
    float* __restrict__ out, int total, int nchunks)
{
    const int tid = threadIdx.x;
    int c = blockIdx.x;

    Buf A, B;
    issue_loads(A, s1, s2, c, tid, total);

#pragma unroll 1
    for (;;) {
        const int cB = c + NB;
        const bool hasB = cB < nchunks;
        if (hasB) issue_loads(B, s1, s2, cB, tid, total);
        __builtin_amdgcn_sched_barrier(0);
        compute_store(A, out, c, tid);
        if (!hasB) break;

        const int cA = c + 2 * NB;
        const bool hasA = cA < nchunks;
        if (hasA) issue_loads(A, s1, s2, cA, tid, total);
        __builtin_amdgcn_sched_barrier(0);
        compute_store(B, out, cB, tid);
        if (!hasA) break;
        c = cA;
    }
}

extern "C" void kernel_launch(void* const* d_in, const int* in_sizes, int n_in,
                              void* d_out, int out_size, void* d_ws, size_t ws_size,
                              hipStream_t stream) {
    const float* s1 = (const float*)d_in[0];
    const float* s2 = (const float*)d_in[1];
    float* out = (float*)d_out;

    const int total = in_sizes[0];        // B * N = 33554432
    const int nchunks = total / CHUNK;    // 16384
    const int blocks = NB < nchunks ? NB : nchunks;  // 2048 -> 8 iters/block

    ssim1d_kernel<<<blocks, BLK, 0, stream>>>(s1, s2, out, total, nchunks);
}

// Round 9
// 98.174 us; speedup vs baseline: 2.2996x; 2.2996x over previous
//
#include <hip/hip_runtime.h>

// SSIM-1D fused: depthwise Gaussian convs (K=11, zero-pad 5) + rational epilogue.
// R9: minimal-live-state + TLP. R8 post-mortem: occupancy hints made the
// allocator spill (WRITE 131->469 MB). Here the thread's logical working set
// is cut to ~60 floats so even a stingy allocation schedules cleanly:
//   window transformed in place to e=s1+s2, f=s1-s2 (t1,t2 die),
//   squares computed on the fly inside the conv (no q arrays),
//   conv(e),conv(f),conv(e^2),conv(f^2) recover all SSIM terms:
//     mu1*mu2=(MS^2-MD^2)/4, mu1^2+mu2^2=(MS^2+MD^2)/2,
//     m12=(SU-SV)/4, m11+m22=(SU+SV)/2.
// 4096 blocks x 4 contiguous chunks: launch rate amortized, no occupancy cap,
// no min-waves hint (avoids the spill heuristic). Latency hidden by TLP.

typedef float f4 __attribute__((ext_vector_type(4)));

constexpr int K = 11;
constexpr int OPT = 8;            // outputs per thread per chunk
constexpr int BLK = 256;          // threads per block
constexpr int CHUNK = OPT * BLK;  // 2048
constexpr int CPB = 4;            // contiguous chunks per block (= 2 rows)

__global__ __launch_bounds__(BLK) void ssim1d_kernel(
    const float* __restrict__ s1, const float* __restrict__ s2,
    float* __restrict__ out, int total)
{
    const int tid = threadIdx.x;
    const int c0 = blockIdx.x * CPB;

    // Gaussian(11, 1.5) normalized (matches numpy float32 to ~1e-7); SGPR consts.
    const float Wt[K] = {0.00102838f, 0.00759876f, 0.03600079f, 0.10936070f,
                         0.21300553f, 0.26601172f, 0.21300553f, 0.10936070f,
                         0.03600079f, 0.00759876f, 0.00102838f};
    const float C1 = 1.0e-4f, C2 = 9.0e-4f;

#pragma unroll 1
    for (int cc = 0; cc < CPB; ++cc) {
        const int c = c0 + cc;
        const int g = c * CHUNK + tid * OPT - 8;  // window base (mult of 4)

        // ---- load 24-float aligned window per signal, 12x dwordx4 batch ----
        f4 a[6], b[6];
#pragma unroll
        for (int i = 0; i < 6; ++i) {
            int ad = g + 4 * i;
            ad = ad < 0 ? 0 : ad;                  // chunk 0 tid 0 (zeroed below)
            ad = ad > total - 4 ? total - 4 : ad;  // last chunk tid 255 (zeroed)
            a[i] = *(const f4*)(s1 + ad);
            b[i] = *(const f4*)(s2 + ad);
        }
        // Zero-pad at row edges (N=4096, 2 chunks/row: parity = row half).
        if (((c & 1) == 0) && tid == 0) {
            a[0] = f4{0.f, 0.f, 0.f, 0.f}; a[1] = f4{0.f, 0.f, 0.f, 0.f};
            b[0] = f4{0.f, 0.f, 0.f, 0.f}; b[1] = f4{0.f, 0.f, 0.f, 0.f};
        }
        if (((c & 1) == 1) && tid == BLK - 1) {
            a[4] = f4{0.f, 0.f, 0.f, 0.f}; a[5] = f4{0.f, 0.f, 0.f, 0.f};
            b[4] = f4{0.f, 0.f, 0.f, 0.f}; b[5] = f4{0.f, 0.f, 0.f, 0.f};
        }

        // ---- in-place transform: e = s1+s2, f = s1-s2 (t1,t2 die here) ----
        float e[24], fd[24];
#pragma unroll
        for (int i = 0; i < 6; ++i) {
#pragma unroll
            for (int j = 0; j < 4; ++j) {
                e[4 * i + j]  = a[i][j] + b[i][j];
                fd[4 * i + j] = a[i][j] - b[i][j];
            }
        }

        // ---- 4 conv streams, squares on the fly (no q arrays) ----
        float res[OPT];
#pragma unroll
        for (int j = 0; j < OPT; ++j) {
            float MS = 0.f, MD = 0.f, SU = 0.f, SV = 0.f;
#pragma unroll
            for (int k = 0; k < K; ++k) {
                const float w = Wt[k];
                const float ev = e[j + k + 3];
                const float fv = fd[j + k + 3];
                MS = fmaf(w, ev, MS);            // -> mu1+mu2
                MD = fmaf(w, fv, MD);            // -> mu1-mu2
                SU = fmaf(w * ev, ev, SU);       // -> E[(s1+s2)^2]
                SV = fmaf(w * fv, fv, SV);       // -> E[(s1-s2)^2]
            }
            const float ms2 = MS * MS, md2 = MD * MD;
            const float mup  = 0.25f * (ms2 - md2);        // mu1*mu2
            const float muq  = 0.5f  * (ms2 + md2);        // mu1^2+mu2^2
            const float s12  = 0.25f * (SU - SV) - mup;    // sigma12
            const float sq   = 0.5f  * (SU + SV) - muq;    // sigma1^2+sigma2^2
            const float num  = fmaf(2.f, mup, C1) * fmaf(2.f, s12, C2);
            const float den  = (muq + C1) * (sq + C2);
            const float ssim = num * __builtin_amdgcn_rcpf(den); // den>=C1*C2>0
            res[j] = 0.5f - 0.5f * ssim;                   // 1 - (ssim+1)/2
        }

        f4* op = (f4*)(out + c * CHUNK + tid * OPT);
        op[0] = *(f4*)&res[0];
        op[1] = *(f4*)&res[4];
    }
}

extern "C" void kernel_launch(void* const* d_in, const int* in_sizes, int n_in,
                              void* d_out, int out_size, void* d_ws, size_t ws_size,
                              hipStream_t stream) {
    const float* s1 = (const float*)d_in[0];
    const float* s2 = (const float*)d_in[1];
    float* out = (float*)d_out;

    const int total = in_sizes[0];             // B * N = 33554432
    const int nchunks = total / CHUNK;         // 16384
    const int blocks = nchunks / CPB;          // 4096

    ssim1d_kernel<<<blocks, BLK, 0, stream>>>(s1, s2, out, total);
}

// Round 10
// 92.171 us; speedup vs baseline: 2.4493x; 1.0651x over previous
//
#include <hip/hip_runtime.h>

// SSIM-1D fused: depthwise Gaussian convs (K=11, zero-pad 5) + rational epilogue.
// R10: champion structure (R1: 16384 one-chunk blocks, fast/slow edge paths,
// no clamps, no chunk loop, no occupancy hints) + the 4-stream sum/diff
// algebra (numerically validated in R8/R9): e=s1+s2, f=s1-s2;
// conv(e),conv(f),conv(w*e*e),conv(w*f*f) give
//   mu1*mu2=(MS^2-MD^2)/4, mu1^2+mu2^2=(MS^2+MD^2)/2,
//   m12=(SU-SV)/4, m11+m22=(SU+SV)/2
// -> one fewer conv stream than the 5-stream form (-8% VALU/output) and
// smaller live set (e[24]+fd[24]+4 accs vs t+q arrays).

typedef float f4 __attribute__((ext_vector_type(4)));

constexpr int K = 11;
constexpr int OPT = 8;            // outputs per thread
constexpr int BLK = 256;          // threads per block
constexpr int CHUNK = OPT * BLK;  // 2048

__global__ __launch_bounds__(BLK) void ssim1d_kernel(
    const float* __restrict__ s1, const float* __restrict__ s2,
    float* __restrict__ out, int N)
{
    const int tid   = threadIdx.x;
    const int bid   = blockIdx.x;
    const int chunks_per_row = N / CHUNK;
    const int chunk = bid % chunks_per_row;
    const int row   = bid / chunks_per_row;
    const int base  = chunk * CHUNK + tid * OPT;
    const size_t rowoff = (size_t)row * (size_t)N;
    const float* r1 = s1 + rowoff;
    const float* r2 = s2 + rowoff;

    // Load 24-float aligned window [base-8, base+16); needed is [base-5, base+13).
    float t1[24], t2[24];
    if (base >= 8 && base <= N - 16) {
        // Fast path: zero per-load overhead, straight base+offset dwordx4.
#pragma unroll
        for (int i = 0; i < 6; ++i) {
            *(f4*)&t1[4 * i] = *(const f4*)(r1 + base - 8 + 4 * i);
            *(f4*)&t2[4 * i] = *(const f4*)(r2 + base - 8 + 4 * i);
        }
    } else {
        // Row-edge slow path (2 threads per row): zero-fill outside [0, N).
#pragma unroll
        for (int j = 0; j < 24; ++j) {
            int idx = base - 8 + j;
            bool ok = (idx >= 0) && (idx < N);
            t1[j] = ok ? r1[idx] : 0.0f;
            t2[j] = ok ? r2[idx] : 0.0f;
        }
    }

    // In-place transform: e = s1+s2, f = s1-s2 (t1,t2 die here).
    float e[24], fd[24];
#pragma unroll
    for (int m = 0; m < 24; ++m) {
        e[m]  = t1[m] + t2[m];
        fd[m] = t1[m] - t2[m];
    }

    // Gaussian(11, 1.5) normalized (matches numpy float32 to ~1e-7); SGPR consts.
    const float Wt[K] = {0.00102838f, 0.00759876f, 0.03600079f, 0.10936070f,
                         0.21300553f, 0.26601172f, 0.21300553f, 0.10936070f,
                         0.03600079f, 0.00759876f, 0.00102838f};
    const float C1 = 1.0e-4f, C2 = 9.0e-4f;

    // 4 conv streams, squares on the fly (no q arrays).
    float res[OPT];
#pragma unroll
    for (int j = 0; j < OPT; ++j) {
        float MS = 0.f, MD = 0.f, SU = 0.f, SV = 0.f;
#pragma unroll
        for (int k = 0; k < K; ++k) {
            const float w  = Wt[k];
            const float ev = e[j + k + 3];
            const float fv = fd[j + k + 3];
            MS = fmaf(w, ev, MS);            // -> mu1+mu2
            MD = fmaf(w, fv, MD);            // -> mu1-mu2
            SU = fmaf(w * ev, ev, SU);       // -> E[(s1+s2)^2]
            SV = fmaf(w * fv, fv, SV);       // -> E[(s1-s2)^2]
        }
        const float ms2  = MS * MS, md2 = MD * MD;
        const float mup  = 0.25f * (ms2 - md2);        // mu1*mu2
        const float muq  = 0.5f  * (ms2 + md2);        // mu1^2+mu2^2
        const float s12  = 0.25f * (SU - SV) - mup;    // sigma12
        const float sq   = 0.5f  * (SU + SV) - muq;    // sigma1^2+sigma2^2
        const float num  = fmaf(2.f, mup, C1) * fmaf(2.f, s12, C2);
        const float den  = (muq + C1) * (sq + C2);
        const float ssim = num * __builtin_amdgcn_rcpf(den);  // den >= C1*C2 > 0
        res[j] = 0.5f - 0.5f * ssim;                          // 1 - (ssim+1)/2
    }

    float* o = out + rowoff + base;
    *(f4*)&o[0] = *(f4*)&res[0];
    *(f4*)&o[4] = *(f4*)&res[4];
}

extern "C" void kernel_launch(void* const* d_in, const int* in_sizes, int n_in,
                              void* d_out, int out_size, void* d_ws, size_t ws_size,
                              hipStream_t stream) {
    const float* s1 = (const float*)d_in[0];
    const float* s2 = (const float*)d_in[1];
    float* out = (float*)d_out;

    const int N = 4096;                 // row length per reference
    const int total = in_sizes[0];      // B * N
    const int B = total / N;
    const int blocks = B * (N / CHUNK); // 16384

    ssim1d_kernel<<<blocks, BLK, 0, stream>>>(s1, s2, out, N);
}